// Round 4
// baseline (365.920 us; speedup 1.0000x reference)
//
#include <hip/hip_runtime.h>
#include <math.h>

// Problem constants (from reference)
#define BB 2
#define CC 8
#define DD 64
#define HH 160
#define WW 160
#define SS (DD*HH*WW)            // 1,638,400 voxels per sample per channel
#define NVOX (BB*SS)             // 3,276,800 total voxels
#define THREADS 256
#define GPT 2                    // float4 groups per thread
#define BLOCKS_PER_SAMPLE (SS/(THREADS*4*GPT))   // 800
#define NBLOCKS (BB*BLOCKS_PER_SAMPLE)           // 1600

#define L2E 1.4426950408889634f
#define LN2 0.6931471805599453f

__device__ __forceinline__ float f4c(const float4& v, int j) {
    return j==0 ? v.x : (j==1 ? v.y : (j==2 ? v.z : v.w));
}
__device__ __forceinline__ int u4c(const uchar4& v, int j) {
    return j==0 ? (int)v.x : (j==1 ? (int)v.y : (j==2 ? (int)v.z : (int)v.w));
}

// Kernel 1: read target (one-hot), write per-voxel label byte, per-block count
// partials; LAST block (atomic ticket) reduces partials -> counts[2][8] and
// fpar[18] (absent masks + pad counts).
__global__ __launch_bounds__(THREADS)
void pass_label(const float* __restrict__ tgt,
                unsigned char* __restrict__ labels,
                unsigned int* __restrict__ cnt_part,
                unsigned int* __restrict__ ticket,
                unsigned int* __restrict__ counts,
                float* __restrict__ fpar) {
    __shared__ unsigned int scnt[CC];
    __shared__ unsigned int sc[2 * CC];
    __shared__ int s_last;
    const int tid = threadIdx.x;
    if (tid < CC) scnt[tid] = 0u;
    __syncthreads();

    const int b   = blockIdx.x / BLOCKS_PER_SAMPLE;
    const int blk = blockIdx.x % BLOCKS_PER_SAMPLE;
    const int S4  = SS / 4;
    const float4* base = (const float4*)(tgt + (size_t)b * CC * SS);
    uchar4* lab4 = (uchar4*)labels + (size_t)b * S4;

    for (int it = 0; it < GPT; ++it) {
        const int g = blk * (THREADS * GPT) + it * THREADS + tid;
        float4 v[CC];
        #pragma unroll
        for (int c = 0; c < CC; ++c) v[c] = base[(size_t)c * S4 + g];

        int l0 = 0, l1 = 0, l2 = 0, l3 = 0;
        #pragma unroll
        for (int c = 1; c < CC; ++c) {
            if (v[c].x > 0.5f) l0 = c;
            if (v[c].y > 0.5f) l1 = c;
            if (v[c].z > 0.5f) l2 = c;
            if (v[c].w > 0.5f) l3 = c;
        }
        uchar4 L;
        L.x = (unsigned char)l0; L.y = (unsigned char)l1;
        L.z = (unsigned char)l2; L.w = (unsigned char)l3;
        lab4[g] = L;
        atomicAdd(&scnt[l0], 1u);   // LDS atomics: uncontended across blocks
        atomicAdd(&scnt[l1], 1u);
        atomicAdd(&scnt[l2], 1u);
        atomicAdd(&scnt[l3], 1u);
    }
    __syncthreads();
    if (tid < CC) cnt_part[tid * NBLOCKS + blockIdx.x] = scnt[tid];

    // last-block-done: release partials, take ticket
    __threadfence();
    if (tid == 0) {
        const unsigned int old = atomicAdd(ticket, 1u);
        s_last = (old == NBLOCKS - 1u);
    }
    __syncthreads();
    if (!s_last) return;
    __threadfence();    // acquire: invalidate stale cached partials

    const int w = tid >> 6, lane = tid & 63;
    for (int q = w; q < CC; q += 4) {
        unsigned int a0 = 0, a1 = 0;
        const unsigned int* col = cnt_part + q * NBLOCKS;
        #pragma unroll
        for (int k = 0; k < NBLOCKS / 64; ++k) {
            const int bk = lane + (k << 6);
            const unsigned int v = col[bk];
            if (bk < BLOCKS_PER_SAMPLE) a0 += v; else a1 += v;
        }
        #pragma unroll
        for (int off = 32; off > 0; off >>= 1) {
            a0 += __shfl_down(a0, off, 64);
            a1 += __shfl_down(a1, off, 64);
        }
        if (lane == 0) { sc[q] = a0; sc[CC + q] = a1; }
    }
    __syncthreads();
    if (tid == 0) {
        int n0 = 0, n1 = 0;
        for (int c = 0; c < CC; ++c) { n0 += (sc[c] > 0u); n1 += (sc[CC + c] > 0u); }
        const int maxn = n0 > n1 ? n0 : n1;
        for (int c = 0; c < CC; ++c) {
            counts[c]      = sc[c];
            counts[CC + c] = sc[CC + c];
            fpar[c]        = (sc[c]      > 0u) ? 0.0f : 1.0f;
            fpar[CC + c]   = (sc[CC + c] > 0u) ? 0.0f : 1.0f;
        }
        fpar[16] = (float)(maxn - n0);
        fpar[17] = (float)(maxn - n1);
    }
}

// Kernel 2: read net_output + labels; per-block partials for seg[8], inter[8],
// ce; LAST block reduces partials and writes the scalar loss.
__global__ __launch_bounds__(THREADS)
void pass_main(const float* __restrict__ net,
               const unsigned char* __restrict__ labels,
               const float* __restrict__ fpar,
               const unsigned int* __restrict__ counts,
               float* __restrict__ part,
               unsigned int* __restrict__ ticket,
               float* __restrict__ out) {
    __shared__ float s_ab[CC];
    __shared__ float s_padf;
    __shared__ float s_red[2 * CC + 1];   // seg[8], inter[8], ce
    __shared__ float sredf[2 * CC + 1][2];
    __shared__ int s_last;

    const int tid = threadIdx.x;
    const int b   = blockIdx.x / BLOCKS_PER_SAMPLE;
    const int blk = blockIdx.x % BLOCKS_PER_SAMPLE;

    if (tid < CC) s_ab[tid] = fpar[b * CC + tid];
    if (tid == CC) s_padf = fpar[2 * CC + b];
    if (tid < 2 * CC + 1) s_red[tid] = 0.0f;
    __syncthreads();

    float ab[CC], bias[CC];
    #pragma unroll
    for (int c = 0; c < CC; ++c) { ab[c] = s_ab[c]; bias[c] = -2048.0f * ab[c]; }
    const float padf = s_padf;

    float segA[CC];
    float intA[CC];
    #pragma unroll
    for (int c = 0; c < CC; ++c) { segA[c] = 0.0f; intA[c] = 0.0f; }
    float ceA = 0.0f;

    const int S4 = SS / 4;
    const float4* base = (const float4*)(net + (size_t)b * CC * SS);
    const uchar4* lab4 = (const uchar4*)labels + (size_t)b * S4;

    for (int it = 0; it < GPT; ++it) {
        const int g = blk * (THREADS * GPT) + it * THREADS + tid;
        float4 v[CC];
        #pragma unroll
        for (int c = 0; c < CC; ++c) v[c] = base[(size_t)c * S4 + g];
        const uchar4 L = lab4[g];

        #pragma unroll
        for (int j = 0; j < 4; ++j) {
            const int lab = u4c(L, j);
            float m[CC];
            m[0] = f4c(v[0], j);
            float fold = 0.0f;
            #pragma unroll
            for (int c = 1; c < CC; ++c) {
                const float x = f4c(v[c], j);
                m[c] = x;
                fold = fmaf(ab[c], x, fold);    // absent foreground -> bg
            }
            m[0] += fold;

            // e[c] = present ? exp(m[c]) : 0   (bias -2048 underflows exp2 to 0)
            float e[CC];
            float se = padf;                    // zero-logit padding: exp(0)*pad
            #pragma unroll
            for (int c = 0; c < CC; ++c) {
                e[c] = __builtin_amdgcn_exp2f(fmaf(m[c], L2E, bias[c]));
                se += e[c];
            }
            const float lse = LN2 * __builtin_amdgcn_logf(se);

            const float sp = se - padf;         // present-only sum (softmax denom)
            float inv = __builtin_amdgcn_rcpf(sp);
            inv = inv * (2.0f - sp * inv);      // 1 Newton step

            float mlab = 0.0f;
            #pragma unroll
            for (int c = 0; c < CC; ++c) {
                const float p = e[c] * inv;
                segA[c] += p;
                const bool isl = (lab == c);
                intA[c] += isl ? p : 0.0f;
                mlab     = isl ? m[c] : mlab;
            }
            ceA += lse - mlab;
        }
    }

    // wave-level reduction (64 lanes) then LDS accumulation
    #pragma unroll
    for (int off = 32; off > 0; off >>= 1) {
        #pragma unroll
        for (int c = 0; c < CC; ++c) {
            segA[c] += __shfl_down(segA[c], off, 64);
            intA[c] += __shfl_down(intA[c], off, 64);
        }
        ceA += __shfl_down(ceA, off, 64);
    }
    if ((tid & 63) == 0) {
        #pragma unroll
        for (int c = 0; c < CC; ++c) {
            atomicAdd(&s_red[c],      segA[c]);
            atomicAdd(&s_red[CC + c], intA[c]);
        }
        atomicAdd(&s_red[2 * CC], ceA);
    }
    __syncthreads();
    // per-block partials: disjoint addresses, plain stores (no contention)
    if (tid < 2 * CC + 1) part[tid * NBLOCKS + blockIdx.x] = s_red[tid];

    // last-block-done: release partials, take ticket
    __threadfence();
    if (tid == 0) {
        const unsigned int old = atomicAdd(ticket, 1u);
        s_last = (old == NBLOCKS - 1u);
    }
    __syncthreads();
    if (!s_last) return;
    __threadfence();    // acquire

    const int w = tid >> 6, lane = tid & 63;
    for (int q = w; q < 2 * CC + 1; q += 4) {
        float a0 = 0.0f, a1 = 0.0f;
        const float* col = part + q * NBLOCKS;
        #pragma unroll
        for (int k = 0; k < NBLOCKS / 64; ++k) {
            const int bk = lane + (k << 6);
            const float v = col[bk];
            if (bk < BLOCKS_PER_SAMPLE) a0 += v; else a1 += v;
        }
        #pragma unroll
        for (int off = 32; off > 0; off >>= 1) {
            a0 += __shfl_down(a0, off, 64);
            a1 += __shfl_down(a1, off, 64);
        }
        if (lane == 0) { sredf[q][0] = a0; sredf[q][1] = a1; }
    }
    __syncthreads();
    if (tid == 0) {
        const float ce = (sredf[2 * CC][0] + sredf[2 * CC][1]) / (float)NVOX;
        float dc = 0.0f;
        for (int bb = 0; bb < BB; ++bb) {
            int nb = 0;
            float acc = 0.0f;
            for (int c = 0; c < CC; ++c) {
                const unsigned int cnt = counts[bb * CC + c];
                if (cnt > 0u) {
                    ++nb;
                    const float R = (float)cnt;
                    const float Sg = sredf[c][bb];
                    const float I  = sredf[CC + c][bb];
                    acc += 2.0f * I / (R + Sg + 1e-5f);
                }
            }
            dc += 1.0f - acc / (float)nb;
        }
        dc /= (float)BB;
        out[0] = 0.5f * ce + 0.5f * dc;
    }
}

extern "C" void kernel_launch(void* const* d_in, const int* in_sizes, int n_in,
                              void* d_out, int out_size, void* d_ws, size_t ws_size,
                              hipStream_t stream) {
    const float* net = (const float*)d_in[0];
    const float* tgt = (const float*)d_in[1];
    float* out = (float*)d_out;

    // workspace layout
    unsigned int* ticket0  = (unsigned int*)d_ws;                          // @0
    unsigned int* ticket1  = (unsigned int*)d_ws + 1;                      // @4
    unsigned int* counts   = (unsigned int*)((char*)d_ws + 64);            // 16 u32  @64
    float*        fpar     = (float*)((char*)d_ws + 128);                  // 18 f32  @128
    unsigned int* cnt_part = (unsigned int*)((char*)d_ws + 256);           // 8*1600  @256    (51200 B)
    float*        part     = (float*)((char*)d_ws + 256 + 51200);          // 17*1600 @51456  (108800 B)
    unsigned char* labels  = (unsigned char*)d_ws + 256 + 51200 + 108800;  // NVOX B  @160256

    hipMemsetAsync(d_ws, 0, 64, stream);   // zero tickets each call (determinism)
    pass_label<<<NBLOCKS, THREADS, 0, stream>>>(tgt, labels, cnt_part, ticket0, counts, fpar);
    pass_main<<<NBLOCKS, THREADS, 0, stream>>>(net, labels, fpar, counts, part, ticket1, out);
}

// Round 5
// 46.711 us; speedup vs baseline: 7.8337x; 7.8337x over previous
//
#include <hip/hip_runtime.h>
#include <math.h>

// Problem constants (from reference)
#define BB 2
#define CC 8
#define DD 64
#define HH 160
#define WW 160
#define SS (DD*HH*WW)            // 1,638,400 voxels per sample per channel
#define NVOX (BB*SS)             // 3,276,800 total voxels
#define THREADS 256
#define GPT 2                    // float4 groups per thread
#define BLOCKS_PER_SAMPLE (SS/(THREADS*4*GPT))   // 800
#define NBLOCKS (BB*BLOCKS_PER_SAMPLE)           // 1600

#define L2E 1.4426950408889634f
#define LN2 0.6931471805599453f

typedef float f32x4 __attribute__((ext_vector_type(4)));

// Kernel 1: read target (one-hot, nontemporal), write packed 4-bit labels
// (ushort per float4-group), per-block count partials (plain stores).
__global__ __launch_bounds__(THREADS)
void pass_label(const f32x4* __restrict__ tgt,
                unsigned short* __restrict__ lab16,
                unsigned int* __restrict__ cnt_part) {
    __shared__ unsigned int scnt[CC];
    const int tid = threadIdx.x;
    if (tid < CC) scnt[tid] = 0u;
    __syncthreads();

    const int b   = blockIdx.x / BLOCKS_PER_SAMPLE;
    const int blk = blockIdx.x % BLOCKS_PER_SAMPLE;
    const int S4  = SS / 4;
    const f32x4* base = tgt + (size_t)b * CC * S4;
    unsigned short* lab = lab16 + (size_t)b * S4;

    for (int it = 0; it < GPT; ++it) {
        const int g = blk * (THREADS * GPT) + it * THREADS + tid;
        f32x4 v[CC];
        #pragma unroll
        for (int c = 0; c < CC; ++c) v[c] = __builtin_nontemporal_load(base + (size_t)c * S4 + g);

        int l0 = 0, l1 = 0, l2 = 0, l3 = 0;
        #pragma unroll
        for (int c = 1; c < CC; ++c) {
            if (v[c][0] > 0.5f) l0 = c;
            if (v[c][1] > 0.5f) l1 = c;
            if (v[c][2] > 0.5f) l2 = c;
            if (v[c][3] > 0.5f) l3 = c;
        }
        lab[g] = (unsigned short)(l0 | (l1 << 4) | (l2 << 8) | (l3 << 12));
        atomicAdd(&scnt[l0], 1u);   // LDS atomics: no cross-block contention
        atomicAdd(&scnt[l1], 1u);
        atomicAdd(&scnt[l2], 1u);
        atomicAdd(&scnt[l3], 1u);
    }
    __syncthreads();
    if (tid < CC) cnt_part[tid * NBLOCKS + blockIdx.x] = scnt[tid];
}

// Tiny: reduce per-block count partials -> counts[2][8] + derived fpar[18]
// (absent masks, pad counts). Kernel boundary = the device-scope fence.
__global__ __launch_bounds__(512)
void reduce_counts(const unsigned int* __restrict__ cnt_part,
                   unsigned int* __restrict__ counts,
                   float* __restrict__ fpar) {
    __shared__ unsigned int sc[2 * CC];
    const int tid = threadIdx.x;
    const int w = tid >> 6, lane = tid & 63;
    unsigned int a0 = 0, a1 = 0;
    const unsigned int* col = cnt_part + w * NBLOCKS;
    #pragma unroll
    for (int k = 0; k < NBLOCKS / 64; ++k) {
        const int blk = lane + (k << 6);
        const unsigned int v = col[blk];
        if (blk < BLOCKS_PER_SAMPLE) a0 += v; else a1 += v;
    }
    #pragma unroll
    for (int off = 32; off > 0; off >>= 1) {
        a0 += __shfl_down(a0, off, 64);
        a1 += __shfl_down(a1, off, 64);
    }
    if (lane == 0) { sc[w] = a0; sc[CC + w] = a1; counts[w] = a0; counts[CC + w] = a1; }
    __syncthreads();
    if (tid == 0) {
        int n0 = 0, n1 = 0;
        for (int c = 0; c < CC; ++c) { n0 += (sc[c] > 0u); n1 += (sc[CC + c] > 0u); }
        const int maxn = n0 > n1 ? n0 : n1;
        for (int c = 0; c < CC; ++c) {
            fpar[c]      = (sc[c]      > 0u) ? 0.0f : 1.0f;
            fpar[CC + c] = (sc[CC + c] > 0u) ? 0.0f : 1.0f;
        }
        fpar[16] = (float)(maxn - n0);
        fpar[17] = (float)(maxn - n1);
    }
}

// Kernel 2: read net_output (nontemporal) + packed labels; per-block partials
// for seg[8], inter[8], ce (plain stores, disjoint addresses).
__global__ __launch_bounds__(THREADS)
void pass_main(const f32x4* __restrict__ net,
               const unsigned short* __restrict__ lab16,
               const float* __restrict__ fpar,
               float* __restrict__ part) {
    __shared__ float s_ab[CC];
    __shared__ float s_padf;
    __shared__ float s_red[2 * CC + 1];   // seg[8], inter[8], ce

    const int tid = threadIdx.x;
    const int b   = blockIdx.x / BLOCKS_PER_SAMPLE;
    const int blk = blockIdx.x % BLOCKS_PER_SAMPLE;

    if (tid < CC) s_ab[tid] = fpar[b * CC + tid];
    if (tid == CC) s_padf = fpar[2 * CC + b];
    if (tid < 2 * CC + 1) s_red[tid] = 0.0f;
    __syncthreads();

    float ab[CC], bias[CC];
    #pragma unroll
    for (int c = 0; c < CC; ++c) { ab[c] = s_ab[c]; bias[c] = -2048.0f * ab[c]; }
    const float padf = s_padf;

    float segA[CC];
    float intA[CC];
    #pragma unroll
    for (int c = 0; c < CC; ++c) { segA[c] = 0.0f; intA[c] = 0.0f; }
    float ceA = 0.0f;

    const int S4 = SS / 4;
    const f32x4* base = net + (size_t)b * CC * S4;
    const unsigned short* lab = lab16 + (size_t)b * S4;

    for (int it = 0; it < GPT; ++it) {
        const int g = blk * (THREADS * GPT) + it * THREADS + tid;
        f32x4 v[CC];
        #pragma unroll
        for (int c = 0; c < CC; ++c) v[c] = __builtin_nontemporal_load(base + (size_t)c * S4 + g);
        const unsigned int Lp = lab[g];

        #pragma unroll
        for (int j = 0; j < 4; ++j) {
            const int lab_j = (Lp >> (4 * j)) & 0xF;
            float m[CC];
            m[0] = v[0][j];
            // absent-foreground fold, explicit pairwise tree (no fast-math reassoc)
            float f1 = ab[1] * v[1][j];
            float f2 = ab[2] * v[2][j];
            float f3 = ab[3] * v[3][j];
            float f4 = ab[4] * v[4][j];
            float f5 = ab[5] * v[5][j];
            float f6 = ab[6] * v[6][j];
            float f7 = ab[7] * v[7][j];
            #pragma unroll
            for (int c = 1; c < CC; ++c) m[c] = v[c][j];
            m[0] += ((f1 + f2) + (f3 + f4)) + ((f5 + f6) + f7);

            // e[c] = present ? exp(m[c]) : 0   (bias -2048 underflows exp2 to 0)
            float e[CC];
            #pragma unroll
            for (int c = 0; c < CC; ++c)
                e[c] = __builtin_amdgcn_exp2f(fmaf(m[c], L2E, bias[c]));
            const float sp = ((e[0] + e[1]) + (e[2] + e[3])) + ((e[4] + e[5]) + (e[6] + e[7]));
            const float se = sp + padf;         // zero-logit padding: exp(0)*pad
            const float lse = LN2 * __builtin_amdgcn_logf(se);

            float inv = __builtin_amdgcn_rcpf(sp);
            inv = inv * (2.0f - sp * inv);      // 1 Newton step

            float mlab = 0.0f;
            #pragma unroll
            for (int c = 0; c < CC; ++c) {
                const float p = e[c] * inv;
                segA[c] += p;
                const bool isl = (lab_j == c);
                intA[c] += isl ? p : 0.0f;
                mlab     = isl ? m[c] : mlab;
            }
            ceA += lse - mlab;
        }
    }

    // wave-level reduction (64 lanes) then LDS accumulation
    #pragma unroll
    for (int off = 32; off > 0; off >>= 1) {
        #pragma unroll
        for (int c = 0; c < CC; ++c) {
            segA[c] += __shfl_down(segA[c], off, 64);
            intA[c] += __shfl_down(intA[c], off, 64);
        }
        ceA += __shfl_down(ceA, off, 64);
    }
    if ((tid & 63) == 0) {
        #pragma unroll
        for (int c = 0; c < CC; ++c) {
            atomicAdd(&s_red[c],      segA[c]);
            atomicAdd(&s_red[CC + c], intA[c]);
        }
        atomicAdd(&s_red[2 * CC], ceA);
    }
    __syncthreads();
    if (tid < 2 * CC + 1) part[tid * NBLOCKS + blockIdx.x] = s_red[tid];
}

__global__ __launch_bounds__(512)
void finalize(const unsigned int* __restrict__ counts,
              const float* __restrict__ part,
              float* __restrict__ out) {
    __shared__ float sred[2 * CC + 1][2];
    const int tid = threadIdx.x;
    const int w = tid >> 6, lane = tid & 63;
    for (int q = w; q < 2 * CC + 1; q += 8) {
        float a0 = 0.0f, a1 = 0.0f;
        const float* col = part + q * NBLOCKS;
        #pragma unroll
        for (int k = 0; k < NBLOCKS / 64; ++k) {
            const int blk = lane + (k << 6);
            const float v = col[blk];
            if (blk < BLOCKS_PER_SAMPLE) a0 += v; else a1 += v;
        }
        #pragma unroll
        for (int off = 32; off > 0; off >>= 1) {
            a0 += __shfl_down(a0, off, 64);
            a1 += __shfl_down(a1, off, 64);
        }
        if (lane == 0) { sred[q][0] = a0; sred[q][1] = a1; }
    }
    __syncthreads();
    if (tid == 0) {
        const float ce = (sred[2 * CC][0] + sred[2 * CC][1]) / (float)NVOX;
        float dc = 0.0f;
        for (int b = 0; b < BB; ++b) {
            int nb = 0;
            float acc = 0.0f;
            for (int c = 0; c < CC; ++c) {
                const unsigned int cnt = counts[b * CC + c];
                if (cnt > 0u) {
                    ++nb;
                    const float R = (float)cnt;
                    const float Sg = sred[c][b];
                    const float I  = sred[CC + c][b];
                    acc += 2.0f * I / (R + Sg + 1e-5f);
                }
            }
            dc += 1.0f - acc / (float)nb;
        }
        dc /= (float)BB;
        out[0] = 0.5f * ce + 0.5f * dc;
    }
}

extern "C" void kernel_launch(void* const* d_in, const int* in_sizes, int n_in,
                              void* d_out, int out_size, void* d_ws, size_t ws_size,
                              hipStream_t stream) {
    const f32x4* net = (const f32x4*)d_in[0];
    const f32x4* tgt = (const f32x4*)d_in[1];
    float* out = (float*)d_out;

    // workspace layout (every slot fully written by its producer — no memset)
    unsigned int*   counts   = (unsigned int*)d_ws;                          // 16 u32  @0
    float*          fpar     = (float*)((char*)d_ws + 64);                   // 18 f32  @64
    unsigned int*   cnt_part = (unsigned int*)((char*)d_ws + 256);           // 8*1600  @256    (51200 B)
    float*          part     = (float*)((char*)d_ws + 256 + 51200);          // 17*1600 @51456  (108800 B)
    unsigned short* lab16    = (unsigned short*)((char*)d_ws + 256 + 51200 + 108800); // NVOX/4 ushort (1.64 MB)

    pass_label<<<NBLOCKS, THREADS, 0, stream>>>(tgt, lab16, cnt_part);
    reduce_counts<<<1, 512, 0, stream>>>(cnt_part, counts, fpar);
    pass_main<<<NBLOCKS, THREADS, 0, stream>>>(net, lab16, fpar, part);
    finalize<<<1, 512, 0, stream>>>(counts, part, out);
}